// Round 1
// baseline (4769.812 us; speedup 1.0000x reference)
//
#include <hip/hip_runtime.h>
#include <hip/hip_bf16.h>

#define T_LEN 512
#define BATCH 8
#define HID   256
#define G4    1024   // 4H
#define EMBD  64
#define VOC   32000
#define KDIM  512    // 2H

typedef __attribute__((ext_vector_type(8))) short bh8;    // 8 bf16 (4 VGPRs)
typedef __attribute__((ext_vector_type(4))) short s4v;    // 4 bf16 (8 B)
typedef __attribute__((ext_vector_type(4))) float fx4;    // 4 fp32

// RNE float->bf16 (same as __float2bfloat16 modulo NaN, which we don't produce)
__device__ inline unsigned short f2b(float f) {
    unsigned u = __builtin_bit_cast(unsigned, f);
    unsigned r = (u + 0x7fffu + ((u >> 16) & 1u)) >> 16;
    return (unsigned short)r;
}

__device__ inline float sigm(float x) { return 1.f / (1.f + __expf(-x)); }
__device__ inline float tanh_f(float x) {
    float e = __expf(-2.f * fabsf(x));
    float r = (1.f - e) / (1.f + e);
    return copysignf(r, x);
}

__device__ inline void gload_lds16(const void* g, void* l) {
    __builtin_amdgcn_global_load_lds(
        (const __attribute__((address_space(1))) void*)g,
        (__attribute__((address_space(3))) void*)l, 16, 0, 0);
}

// ---------------------------------------------------------------------------
// Prep: [0,256) WhT (2 dirs), [256,2256) Wt = W_out^T bf16, [2256,2768) x_proj
// ---------------------------------------------------------------------------
__global__ __launch_bounds__(256, 2) void prep_kernel(
    const int* __restrict__ x, const float* __restrict__ emb,
    const float* __restrict__ Wi_f, const float* __restrict__ Wh_f, const float* __restrict__ b_f,
    const float* __restrict__ Wi_b, const float* __restrict__ Wh_b, const float* __restrict__ b_b,
    const float* __restrict__ W_out,
    float* __restrict__ xp_f, float* __restrict__ xp_b,
    unsigned short* __restrict__ WhT_f, unsigned short* __restrict__ WhT_b,
    unsigned short* __restrict__ Wt)
{
    __shared__ float lds[128 * 65];
    __shared__ int xidx[16];
    const int bid = blockIdx.x, tid = threadIdx.x;

    if (bid < 256) {
        // WhT[n][k] = bf16(Wh[k][n]);  tile: 32 k x 64 n
        const int dir = bid >> 7, b2 = bid & 127;
        const float* Wh = dir ? Wh_b : Wh_f;
        unsigned short* WhT = dir ? WhT_b : WhT_f;
        const int k0 = (b2 >> 4) * 32, n0 = (b2 & 15) * 64;
        for (int it = 0; it < 8; ++it) {
            int idx = it * 256 + tid, kk = idx >> 6, nn = idx & 63;
            lds[kk * 65 + nn] = Wh[(k0 + kk) * G4 + n0 + nn];
        }
        __syncthreads();
        int nn = tid >> 2, kq = (tid & 3) * 8;
        bh8 v;
        #pragma unroll
        for (int j = 0; j < 8; ++j) v[j] = (short)f2b(lds[(kq + j) * 65 + nn]);
        *(bh8*)&WhT[(size_t)(n0 + nn) * HID + k0 + kq] = v;
    } else if (bid < 2256) {
        // Wt[n][k] = bf16(W_out[k][n]);  tile: 128 k x 64 n
        const int b2 = bid - 256;
        const int k0 = (b2 / 500) * 128, n0 = (b2 % 500) * 64;
        for (int it = 0; it < 32; ++it) {
            int idx = it * 256 + tid, kk = idx >> 6, nn = idx & 63;
            lds[kk * 65 + nn] = W_out[(size_t)(k0 + kk) * VOC + n0 + nn];
        }
        __syncthreads();
        const int kq = (tid & 15) * 8;
        #pragma unroll
        for (int g = 0; g < 4; ++g) {
            int nn = (tid >> 4) + g * 16;
            bh8 v;
            #pragma unroll
            for (int j = 0; j < 8; ++j) v[j] = (short)f2b(lds[(kq + j) * 65 + nn]);
            *(bh8*)&Wt[(size_t)(n0 + nn) * KDIM + k0 + kq] = v;
        }
    } else {
        // x_proj[t][b][g] = b[g] + sum_e emb[x[b,t]][e] * Wi[e][g]; 16 rows/block
        const int b2 = bid - 2256;
        const int dir = b2 >> 8, rb = b2 & 255;
        const float* Wi = dir ? Wi_b : Wi_f;
        const float* bias = dir ? b_b : b_f;
        float* xp = dir ? xp_b : xp_f;
        const int f0 = rb * 16;
        if (tid < 16) {
            int f = f0 + tid, t = f >> 3, b = f & 7;
            xidx[tid] = x[b * T_LEN + t];
        }
        __syncthreads();
        {
            int rr = tid >> 4, e4 = (tid & 15) * 4;
            const float* er = emb + (size_t)xidx[rr] * EMBD + e4;
            lds[rr * 64 + e4 + 0] = er[0];
            lds[rr * 64 + e4 + 1] = er[1];
            lds[rr * 64 + e4 + 2] = er[2];
            lds[rr * 64 + e4 + 3] = er[3];
        }
        __syncthreads();
        const int g0 = tid * 4;
        float acc[16][4];
        float b0 = bias[g0], b1 = bias[g0 + 1], b2b = bias[g0 + 2], b3 = bias[g0 + 3];
        #pragma unroll
        for (int rr = 0; rr < 16; ++rr) {
            acc[rr][0] = b0; acc[rr][1] = b1; acc[rr][2] = b2b; acc[rr][3] = b3;
        }
        for (int e = 0; e < 64; ++e) {
            const float* wp = Wi + e * G4 + g0;
            float w0 = wp[0], w1 = wp[1], w2 = wp[2], w3 = wp[3];
            #pragma unroll
            for (int rr = 0; rr < 16; ++rr) {
                float xv = lds[rr * 64 + e];
                acc[rr][0] += xv * w0; acc[rr][1] += xv * w1;
                acc[rr][2] += xv * w2; acc[rr][3] += xv * w3;
            }
        }
        #pragma unroll
        for (int rr = 0; rr < 16; ++rr) {
            float* dst = xp + (size_t)(f0 + rr) * G4 + g0;
            dst[0] = acc[rr][0]; dst[1] = acc[rr][1];
            dst[2] = acc[rr][2]; dst[3] = acc[rr][3];
        }
    }
}

// ---------------------------------------------------------------------------
// Recurrence: 2 blocks (one per direction), 1024 threads = 16 waves.
// Per wave: 64 gate-columns, Wh slice pre-loaded as 4x8 bf16 MFMA B-fragments.
// M=16 (8 batches + 8 zero-pad rows), K=256, N=1024 per step.
// ---------------------------------------------------------------------------
__global__ __launch_bounds__(1024, 4) void lstm_kernel(
    const float* __restrict__ xp_f, const float* __restrict__ xp_b,
    const unsigned short* __restrict__ WhT_f, const unsigned short* __restrict__ WhT_b,
    unsigned short* __restrict__ h2)
{
    const int dir = blockIdx.x;
    const float* xp = dir ? xp_b : xp_f;
    const unsigned short* WhT = dir ? WhT_b : WhT_f;
    const int tid = threadIdx.x;
    const int w = tid >> 6, lane = tid & 63, quad = lane >> 4, l15 = lane & 15;
    const int colBase = w * 64;

    __shared__ unsigned short hlds[16 * 264];   // [16 rows][256 bf16 + 8 pad]
    __shared__ float gbuf[4 * 8 * 256];         // [gate][batch][hc]

    for (int i = tid; i < 16 * 264; i += 1024) hlds[i] = 0;

    // Pre-load Wh B-fragments: bfr[nt][kt] holds B[k=kt*32+quad*8+j][n=colBase+nt*16+l15]
    bh8 bfr[4][8];
    #pragma unroll
    for (int nt = 0; nt < 4; ++nt)
        #pragma unroll
        for (int kt = 0; kt < 8; ++kt)
            bfr[nt][kt] = *(const bh8*)&WhT[(size_t)(colBase + nt * 16 + l15) * HID + kt * 32 + quad * 8];

    fx4 c = (fx4){0.f, 0.f, 0.f, 0.f};
    __syncthreads();

    for (int s = 0; s < T_LEN; ++s) {
        const int t = dir ? (T_LEN - 1 - s) : s;

        // acc init = x_proj (rows = batches; pad rows -> 0)
        fx4 acc[4];
        #pragma unroll
        for (int nt = 0; nt < 4; ++nt) {
            if (quad < 2) {
                const float* p = xp + ((size_t)t * BATCH + quad * 4) * G4 + colBase + nt * 16 + l15;
                acc[nt][0] = p[0]; acc[nt][1] = p[G4]; acc[nt][2] = p[2 * G4]; acc[nt][3] = p[3 * G4];
            } else {
                acc[nt] = (fx4){0.f, 0.f, 0.f, 0.f};
            }
        }
        // A-fragments of h: A[m=l15][k=kt*32+quad*8+j]
        bh8 af[8];
        #pragma unroll
        for (int kt = 0; kt < 8; ++kt)
            af[kt] = *(const bh8*)&hlds[l15 * 264 + kt * 32 + quad * 8];
        // gates = x_proj + h @ Wh
        #pragma unroll
        for (int nt = 0; nt < 4; ++nt)
            #pragma unroll
            for (int kt = 0; kt < 8; ++kt)
                acc[nt] = __builtin_amdgcn_mfma_f32_16x16x32_bf16(af[kt], bfr[nt][kt], acc[nt], 0, 0, 0);

        // activations, scatter to gbuf (quads 0,1 own batches 0..7)
        #pragma unroll
        for (int nt = 0; nt < 4; ++nt) {
            const int col = colBase + nt * 16 + l15;
            const int gt = col >> 8, hc = col & 255;
            if (quad < 2) {
                #pragma unroll
                for (int v = 0; v < 4; ++v) {
                    float xv = acc[nt][v];
                    float a = (gt == 2) ? tanh_f(xv) : sigm(xv);
                    gbuf[gt * 2048 + (quad * 4 + v) * 256 + hc] = a;
                }
            }
        }
        __syncthreads();

        // c,h update: 512 threads own (batch, 4 hidden cols) each
        if (tid < 512) {
            const int b = tid >> 6, hc0 = (tid & 63) * 4;
            const fx4 fv = *(const fx4*)&gbuf[0 * 2048 + b * 256 + hc0];
            const fx4 iv = *(const fx4*)&gbuf[1 * 2048 + b * 256 + hc0];
            const fx4 gv = *(const fx4*)&gbuf[2 * 2048 + b * 256 + hc0];
            const fx4 ov = *(const fx4*)&gbuf[3 * 2048 + b * 256 + hc0];
            s4v hv;
            #pragma unroll
            for (int j = 0; j < 4; ++j) {
                c[j] = fv[j] * c[j] + iv[j] * gv[j];
                float h = ov[j] * tanh_f(c[j]);
                hv[j] = (short)f2b(h);
            }
            *(s4v*)&hlds[b * 264 + hc0] = hv;
            *(s4v*)&h2[((size_t)b * T_LEN + t) * KDIM + dir * HID + hc0] = hv;
        }
        __syncthreads();
    }
}

// ---------------------------------------------------------------------------
// Output GEMM (m97-style): C[4096][32000] = A[4096][512] * Bt[32000][512]^T + b
// 128x128 tile, BK=32, 256 threads (4 waves, 2x2), global_load_lds staging.
// ---------------------------------------------------------------------------
__global__ __launch_bounds__(256, 2) void gemm_kernel(
    const unsigned short* __restrict__ A,   // h2 bf16 [4096][512]
    const unsigned short* __restrict__ Bt,  // Wt bf16 [32000][512]
    const float* __restrict__ b_out,
    float* __restrict__ out)
{
    const int bid = blockIdx.x;
    const int nb = bid % 250, mb = bid / 250;
    const int tid = threadIdx.x;
    const int wv = tid >> 6, lane = tid & 63, quad = lane >> 4, l15 = lane & 15;
    const int mrow0 = (wv >> 1) * 64, ncol0 = (wv & 1) * 64;

    __shared__ unsigned short smA[128 * 32];
    __shared__ unsigned short smB[128 * 32];

    fx4 acc[4][4];
    #pragma unroll
    for (int i = 0; i < 4; ++i)
        #pragma unroll
        for (int j = 0; j < 4; ++j) acc[i][j] = (fx4){0.f, 0.f, 0.f, 0.f};

    for (int kb = 0; kb < 16; ++kb) {
        __syncthreads();
        #pragma unroll
        for (int i = 0; i < 2; ++i) {
            const int f = ((i * 4 + wv) * 64 + lane) * 16;  // byte offset in 8KB tile
            const int r = f >> 6, cb = f & 63;
            const char* ga = (const char*)A + ((size_t)(mb * 128 + r) * KDIM + kb * 32) * 2 + cb;
            gload_lds16(ga, (char*)smA + (i * 4 + wv) * 1024);
            const char* gb = (const char*)Bt + ((size_t)(nb * 128 + r) * KDIM + kb * 32) * 2 + cb;
            gload_lds16(gb, (char*)smB + (i * 4 + wv) * 1024);
        }
        __syncthreads();
        bh8 a[4], b[4];
        #pragma unroll
        for (int mt = 0; mt < 4; ++mt)
            a[mt] = *(const bh8*)&smA[(mrow0 + mt * 16 + l15) * 32 + quad * 8];
        #pragma unroll
        for (int nt = 0; nt < 4; ++nt)
            b[nt] = *(const bh8*)&smB[(ncol0 + nt * 16 + l15) * 32 + quad * 8];
        #pragma unroll
        for (int mt = 0; mt < 4; ++mt)
            #pragma unroll
            for (int nt = 0; nt < 4; ++nt)
                acc[mt][nt] = __builtin_amdgcn_mfma_f32_16x16x32_bf16(a[mt], b[nt], acc[mt][nt], 0, 0, 0);
    }

    float bia[4];
    #pragma unroll
    for (int nt = 0; nt < 4; ++nt)
        bia[nt] = b_out[nb * 128 + ncol0 + nt * 16 + l15];
    #pragma unroll
    for (int mt = 0; mt < 4; ++mt) {
        const int grow0 = mb * 128 + mrow0 + mt * 16 + quad * 4;
        #pragma unroll
        for (int nt = 0; nt < 4; ++nt) {
            const int gcol = nb * 128 + ncol0 + nt * 16 + l15;
            #pragma unroll
            for (int v = 0; v < 4; ++v)
                out[(size_t)(grow0 + v) * VOC + gcol] = acc[mt][nt][v] + bia[nt];
        }
    }
}

// ---------------------------------------------------------------------------
extern "C" void kernel_launch(void* const* d_in, const int* in_sizes, int n_in,
                              void* d_out, int out_size, void* d_ws, size_t ws_size,
                              hipStream_t stream) {
    const int*   x     = (const int*)d_in[0];
    const float* emb   = (const float*)d_in[1];
    const float* Wi_f  = (const float*)d_in[2];
    const float* Wh_f  = (const float*)d_in[3];
    const float* b_f   = (const float*)d_in[4];
    const float* Wi_b  = (const float*)d_in[5];
    const float* Wh_b  = (const float*)d_in[6];
    const float* b_b   = (const float*)d_in[7];
    const float* W_out = (const float*)d_in[8];
    const float* b_out = (const float*)d_in[9];
    float* out = (float*)d_out;

    char* ws = (char*)d_ws;
    float* xp_f          = (float*)(ws);                       // 16,777,216 B
    float* xp_b          = (float*)(ws + 16777216);            // 16,777,216 B
    unsigned short* WhT_f = (unsigned short*)(ws + 33554432);  //    524,288 B
    unsigned short* WhT_b = (unsigned short*)(ws + 34078720);  //    524,288 B
    unsigned short* Wt    = (unsigned short*)(ws + 34603008);  // 32,768,000 B
    unsigned short* h2    = (unsigned short*)(ws + 67371008);  //  4,194,304 B  (total ~71.6 MB)

    prep_kernel<<<2768, 256, 0, stream>>>(x, emb, Wi_f, Wh_f, b_f, Wi_b, Wh_b, b_b,
                                          W_out, xp_f, xp_b, WhT_f, WhT_b, Wt);
    lstm_kernel<<<2, 1024, 0, stream>>>(xp_f, xp_b, WhT_f, WhT_b, h2);
    gemm_kernel<<<8000, 256, 0, stream>>>(h2, Wt, b_out, out);
}